// Round 10
// baseline (388.160 us; speedup 1.0000x reference)
//
#include <hip/hip_runtime.h>
#include <math.h>

#define NN 50000
#define NE 800000
#define INF_DIM 256
#define HIDF 64
#define NC 32
#define SLOPE 0.2f

__device__ __forceinline__ float elem4(const float4& v, int kk){
  switch(kk){ case 0: return v.x; case 1: return v.y; case 2: return v.z; default: return v.w; }
}

// ============================ CSR build ============================

__global__ void k_zero(int* __restrict__ counts){
  int i = blockIdx.x*blockDim.x + threadIdx.x;
  if(i < NN) counts[i] = 0;
}

__global__ void k_hist(const int* __restrict__ dst, int* __restrict__ counts){
  int e = blockIdx.x*blockDim.x + threadIdx.x;
  if(e < NE) atomicAdd(&counts[dst[e]], 1);
}

__global__ void k_scan_a(const int* __restrict__ counts, int* __restrict__ rowstart,
                         int* __restrict__ blocksums){
  __shared__ int wsum[4];
  int tid = threadIdx.x;
  int idx = blockIdx.x*1024 + tid*4;
  int v0 = (idx+0<NN)?counts[idx+0]:0;
  int v1 = (idx+1<NN)?counts[idx+1]:0;
  int v2 = (idx+2<NN)?counts[idx+2]:0;
  int v3 = (idx+3<NN)?counts[idx+3]:0;
  int s0=v0, s1=s0+v1, s2=s1+v2, s3=s2+v3;
  int lane = tid & 63, w = tid >> 6;
  int x = s3;
  #pragma unroll
  for(int off=1; off<64; off<<=1){
    int y = __shfl_up(x, off, 64);
    if(lane >= off) x += y;
  }
  if(lane==63) wsum[w] = x;
  __syncthreads();
  int woff = 0;
  for(int i=0;i<w;i++) woff += wsum[i];
  int excl = woff + (x - s3);
  if(idx+0<NN) rowstart[idx+1] = excl + s0;
  if(idx+1<NN) rowstart[idx+2] = excl + s1;
  if(idx+2<NN) rowstart[idx+3] = excl + s2;
  if(idx+3<NN) rowstart[idx+4] = excl + s3;
  if(tid==0) blocksums[blockIdx.x] = wsum[0]+wsum[1]+wsum[2]+wsum[3];
}

__global__ void k_scan_b(const int* __restrict__ blocksums, int* __restrict__ blockoff){
  int lane = threadIdx.x;
  const int nb = (NN + 1023)/1024;
  int v = (lane<nb)? blocksums[lane] : 0;
  int x = v;
  #pragma unroll
  for(int off=1; off<64; off<<=1){
    int y = __shfl_up(x, off, 64);
    if(lane >= off) x += y;
  }
  if(lane<nb) blockoff[lane] = x - v;
}

__global__ void k_scan_c(const int* __restrict__ counts, int* __restrict__ rowstart,
                         const int* __restrict__ blockoff, int* __restrict__ cursor){
  int i = blockIdx.x*blockDim.x + threadIdx.x;
  if(i < NN){
    int incl = rowstart[i+1] + blockoff[i>>10];
    rowstart[i+1] = incl;
    cursor[i] = incl - counts[i];
    if(i==0) rowstart[0] = 0;
  }
}

__global__ void k_scatter(const int* __restrict__ src, const int* __restrict__ dst,
                          int* __restrict__ cursor, int* __restrict__ ssrc){
  int e = blockIdx.x*blockDim.x + threadIdx.x;
  if(e < NE){
    int d = dst[e];
    int pos = atomicAdd(&cursor[d], 1);
    ssrc[pos] = src[e];
  }
}

// ============================ GEMM 1: h1 = x @ W1, fused a_src/a_dst dots ===
// 64-thread (1-wave) blocks, 8 nodes/wave, lane = one output column.
// Grid 6250 (exactly 50000 nodes) -> 24 waves/CU of TLP. Per k-step:
// 8 v_fma (acc[i] += x[node i][k] * w) + 1 coalesced W load (W[k][lane],
// 256B, L1-hot 16KB). x loads are wave-uniform (blockIdx-only addressing)
// -> scalarizable, dedup to 16B at L1. No LDS, no barriers, no shuffles
// in the main loop. 4-k slices double-buffered in registers.

__global__ __launch_bounds__(64) void k_gemm1(
    const float* __restrict__ x, const float* __restrict__ W,
    const float* __restrict__ a_s, const float* __restrict__ a_d,
    float* __restrict__ h, float* __restrict__ as_o, float* __restrict__ ad_o){
  int c = threadIdx.x;                 // column 0..63
  int nb = blockIdx.x*8;               // node base (uniform); grid exact
  const float* wc = W + c;

  float acc[8];
  #pragma unroll
  for(int i=0;i<8;i++) acc[i] = 0.f;

  float4 xs[2][8];                     // [parity][node] 4-k slice of x
  float  wr[2][4];                     // [parity][kk]  W column values

  #pragma unroll
  for(int i=0;i<8;i++) xs[0][i] = *(const float4*)(x + (size_t)(nb+i)*INF_DIM);
  #pragma unroll
  for(int kk=0;kk<4;kk++) wr[0][kk] = wc[kk*64];

  #pragma unroll 2
  for(int st=0; st<64; ++st){
    int buf = st & 1, nxt = buf ^ 1;
    if(st < 63){
      int k0 = (st+1)*4;
      #pragma unroll
      for(int i=0;i<8;i++)
        xs[nxt][i] = *(const float4*)(x + (size_t)(nb+i)*INF_DIM + k0);
      #pragma unroll
      for(int kk=0;kk<4;kk++) wr[nxt][kk] = wc[(k0+kk)*64];
    }
    #pragma unroll
    for(int kk=0;kk<4;kk++){
      float w = wr[buf][kk];
      #pragma unroll
      for(int i=0;i<8;i++) acc[i] += elem4(xs[buf][i], kk) * w;
    }
  }

  // epilogue: h rows + fused a-dots (reduce over all 64 lanes)
  float asc = a_s[c], adc = a_d[c];
  #pragma unroll
  for(int i=0;i<8;i++){
    int n = nb + i;
    h[(size_t)n*HIDF + c] = acc[i];
    float sv = acc[i]*asc, dv = acc[i]*adc;
    #pragma unroll
    for(int mk=1; mk<64; mk<<=1){
      sv += __shfl_xor(sv, mk, 64);
      dv += __shfl_xor(dv, mk, 64);
    }
    if(c==0){ as_o[n]=sv; ad_o[n]=dv; }
  }
}

// ============================ Aggregation layer 1 ===========================

__global__ __launch_bounds__(256) void k_agg1(
    const float* __restrict__ h1, const float* __restrict__ as1, const float* __restrict__ ad1,
    const int* __restrict__ rowstart, const int* __restrict__ ssrc,
    float* __restrict__ r1){
  int lane = threadIdx.x & 63;
  int n = blockIdx.x*4 + (threadIdx.x >> 6);
  int rs = rowstart[n], re = rowstart[n+1];
  float adn = ad1[n];
  float m = -1e30f, l = 0.f, acc = 0.f;
  for(int base=rs; base<re; base+=64){
    int cnt = re - base; if(cnt > 64) cnt = 64;
    int s = 0; float z = -1e30f;
    if(lane < cnt){
      s = ssrc[base+lane];
      float zz = as1[s] + adn;
      z = zz > 0.f ? zz : SLOPE*zz;
    }
    float cm = z;
    #pragma unroll
    for(int off=32; off>=1; off>>=1) cm = fmaxf(cm, __shfl_xor(cm, off, 64));
    float nm = fmaxf(m, cm);
    float sc = __expf(m - nm);
    float p = (lane<cnt) ? __expf(z - nm) : 0.f;
    float cs = p;
    #pragma unroll
    for(int off=32; off>=1; off>>=1) cs += __shfl_xor(cs, off, 64);
    l = l*sc + cs;
    acc *= sc;
    int e = 0;
    for(; e+4<=cnt; e+=4){
      int   se0 = __shfl(s, e,   64), se1 = __shfl(s, e+1, 64);
      int   se2 = __shfl(s, e+2, 64), se3 = __shfl(s, e+3, 64);
      float pe0 = __shfl(p, e,   64), pe1 = __shfl(p, e+1, 64);
      float pe2 = __shfl(p, e+2, 64), pe3 = __shfl(p, e+3, 64);
      float v0 = h1[(size_t)se0*HIDF + lane];
      float v1 = h1[(size_t)se1*HIDF + lane];
      float v2 = h1[(size_t)se2*HIDF + lane];
      float v3 = h1[(size_t)se3*HIDF + lane];
      acc += pe0*v0; acc += pe1*v1; acc += pe2*v2; acc += pe3*v3;
    }
    for(; e<cnt; ++e){
      int   se = __shfl(s, e, 64);
      float pe = __shfl(p, e, 64);
      acc += pe * h1[(size_t)se*HIDF + lane];
    }
    m = nm;
  }
  float o = (l > 0.f) ? acc/l : 0.f;
  r1[(size_t)n*HIDF + lane] = fmaxf(o, 0.f);
}

// ============================ GEMM 2: h2 = r1 @ W2, fused a dots ============
// Same streaming structure: 64-thread blocks, wave = 16 nodes x 32 cols.
// lane: c=lane&31 (col), g=lane>>5 (node half). acc[8]; K=64 in 16 slices.

__global__ __launch_bounds__(64) void k_gemm2(
    const float* __restrict__ r1, const float* __restrict__ W2,
    const float* __restrict__ a_s, const float* __restrict__ a_d,
    float* __restrict__ h2, float* __restrict__ as_o, float* __restrict__ ad_o){
  int lane = threadIdx.x;
  int c = lane & 31;
  int g = lane >> 5;
  int nb = blockIdx.x*16 + g*8;        // grid exact: 3125*16 = 50000
  const float* wc = W2 + c;

  float acc[8];
  #pragma unroll
  for(int i=0;i<8;i++) acc[i] = 0.f;

  float4 xs[2][8];
  float  wr[2][4];

  #pragma unroll
  for(int i=0;i<8;i++) xs[0][i] = *(const float4*)(r1 + (size_t)(nb+i)*HIDF);
  #pragma unroll
  for(int kk=0;kk<4;kk++) wr[0][kk] = wc[kk*32];

  #pragma unroll 2
  for(int st=0; st<16; ++st){
    int buf = st & 1, nxt = buf ^ 1;
    if(st < 15){
      int k0 = (st+1)*4;
      #pragma unroll
      for(int i=0;i<8;i++)
        xs[nxt][i] = *(const float4*)(r1 + (size_t)(nb+i)*HIDF + k0);
      #pragma unroll
      for(int kk=0;kk<4;kk++) wr[nxt][kk] = wc[(k0+kk)*32];
    }
    #pragma unroll
    for(int kk=0;kk<4;kk++){
      float w = wr[buf][kk];
      #pragma unroll
      for(int i=0;i<8;i++) acc[i] += elem4(xs[buf][i], kk) * w;
    }
  }

  float asc = a_s[c], adc = a_d[c];
  #pragma unroll
  for(int i=0;i<8;i++){
    int n = nb + i;
    h2[(size_t)n*NC + c] = acc[i];
    float sv = acc[i]*asc, dv = acc[i]*adc;
    #pragma unroll
    for(int mk=1; mk<32; mk<<=1){       // reduce within the 32-lane half
      sv += __shfl_xor(sv, mk, 64);
      dv += __shfl_xor(dv, mk, 64);
    }
    if(c==0){ as_o[n]=sv; ad_o[n]=dv; }
  }
}

// ============================ Aggregation layer 2 ===========================

__global__ __launch_bounds__(256) void k_agg2(
    const float* __restrict__ h2, const float* __restrict__ as2, const float* __restrict__ ad2,
    const int* __restrict__ rowstart, const int* __restrict__ ssrc,
    float* __restrict__ out){
  int tid = threadIdx.x;
  int c = tid & 31;
  int n = blockIdx.x*8 + (tid >> 5);
  int rs = rowstart[n], re = rowstart[n+1];
  float adn = ad2[n];
  float m = -1e30f, l = 0.f, acc = 0.f;
  for(int base=rs; base<re; base+=32){
    int cnt = re - base; if(cnt > 32) cnt = 32;
    int s = 0; float z = -1e30f;
    if(c < cnt){
      s = ssrc[base+c];
      float zz = as2[s] + adn;
      z = zz > 0.f ? zz : SLOPE*zz;
    }
    float cm = z;
    #pragma unroll
    for(int off=16; off>=1; off>>=1) cm = fmaxf(cm, __shfl_xor(cm, off, 32));
    float nm = fmaxf(m, cm);
    float sc = __expf(m - nm);
    float p = (c<cnt) ? __expf(z - nm) : 0.f;
    float cs = p;
    #pragma unroll
    for(int off=16; off>=1; off>>=1) cs += __shfl_xor(cs, off, 32);
    l = l*sc + cs;
    acc *= sc;
    int e = 0;
    for(; e+4<=cnt; e+=4){
      int   se0 = __shfl(s, e,   32), se1 = __shfl(s, e+1, 32);
      int   se2 = __shfl(s, e+2, 32), se3 = __shfl(s, e+3, 32);
      float pe0 = __shfl(p, e,   32), pe1 = __shfl(p, e+1, 32);
      float pe2 = __shfl(p, e+2, 32), pe3 = __shfl(p, e+3, 32);
      float v0 = h2[(size_t)se0*NC + c];
      float v1 = h2[(size_t)se1*NC + c];
      float v2 = h2[(size_t)se2*NC + c];
      float v3 = h2[(size_t)se3*NC + c];
      acc += pe0*v0; acc += pe1*v1; acc += pe2*v2; acc += pe3*v3;
    }
    for(; e<cnt; ++e){
      int   se = __shfl(s, e, 32);
      float pe = __shfl(p, e, 32);
      acc += pe * h2[(size_t)se*NC + c];
    }
    m = nm;
  }
  out[(size_t)n*NC + c] = (l > 0.f) ? acc/l : 0.f;
}

// ============================ launch ============================

extern "C" void kernel_launch(void* const* d_in, const int* in_sizes, int n_in,
                              void* d_out, int out_size, void* d_ws, size_t ws_size,
                              hipStream_t stream){
  const float* x   = (const float*)d_in[0];
  const int*   ei  = (const int*)d_in[1];
  const float* W1  = (const float*)d_in[2];
  const float* a1s = (const float*)d_in[3];
  const float* a1d = (const float*)d_in[4];
  const float* W2  = (const float*)d_in[5];
  const float* a2s = (const float*)d_in[6];
  const float* a2d = (const float*)d_in[7];
  const int* srcIdx = ei;
  const int* dstIdx = ei + NE;
  float* out = (float*)d_out;

  char* wsp = (char*)d_ws;
  size_t off = 0;
  auto alloc = [&](size_t bytes)->void*{
    void* p = wsp + off;
    off = (off + bytes + 255) & ~(size_t)255;
    return p;
  };
  int* counts    = (int*)alloc((size_t)NN*sizeof(int));
  int* rowstart  = (int*)alloc((size_t)(NN+1)*sizeof(int));
  int* cursor    = (int*)alloc((size_t)NN*sizeof(int));
  int* blocksums = (int*)alloc(64*sizeof(int));
  int* blockoff  = (int*)alloc(64*sizeof(int));
  int* ssrc      = (int*)alloc((size_t)NE*sizeof(int));
  float* h1      = (float*)alloc((size_t)NN*HIDF*sizeof(float));
  float* as1     = (float*)alloc((size_t)NN*sizeof(float));
  float* ad1     = (float*)alloc((size_t)NN*sizeof(float));
  float* r1      = (float*)alloc((size_t)NN*HIDF*sizeof(float));
  float* h2  = h1;
  float* as2 = as1;
  float* ad2 = ad1;

  k_zero   <<<(NN+255)/256, 256, 0, stream>>>(counts);
  k_hist   <<<(NE+255)/256, 256, 0, stream>>>(dstIdx, counts);
  k_scan_a <<<(NN+1023)/1024, 256, 0, stream>>>(counts, rowstart, blocksums);
  k_scan_b <<<1, 64, 0, stream>>>(blocksums, blockoff);
  k_scan_c <<<(NN+255)/256, 256, 0, stream>>>(counts, rowstart, blockoff, cursor);
  k_scatter<<<(NE+255)/256, 256, 0, stream>>>(srcIdx, dstIdx, cursor, ssrc);

  k_gemm1<<<NN/8, 64, 0, stream>>>(x, W1, a1s, a1d, h1, as1, ad1);
  k_agg1 <<<NN/4, 256, 0, stream>>>(h1, as1, ad1, rowstart, ssrc, r1);

  k_gemm2<<<NN/16, 64, 0, stream>>>(r1, W2, a2s, a2d, h2, as2, ad2);
  k_agg2 <<<NN/8, 256, 0, stream>>>(h2, as2, ad2, rowstart, ssrc, out);
}

// Round 11
// 305.394 us; speedup vs baseline: 1.2710x; 1.2710x over previous
//
#include <hip/hip_runtime.h>
#include <math.h>

#define NN 50000
#define NE 800000
#define INF_DIM 256
#define HIDF 64
#define NC 32
#define SLOPE 0.2f

__device__ __forceinline__ float elem4(const float4& v, int kk){
  switch(kk){ case 0: return v.x; case 1: return v.y; case 2: return v.z; default: return v.w; }
}
#define FMA4(A,S,V) {A.x += (S)*(V).x; A.y += (S)*(V).y; A.z += (S)*(V).z; A.w += (S)*(V).w;}

// ============================ CSR build ============================

__global__ void k_zero(int* __restrict__ counts){
  int i = blockIdx.x*blockDim.x + threadIdx.x;
  if(i < NN) counts[i] = 0;
}

__global__ void k_hist(const int* __restrict__ dst, int* __restrict__ counts){
  int e = blockIdx.x*blockDim.x + threadIdx.x;
  if(e < NE) atomicAdd(&counts[dst[e]], 1);
}

__global__ void k_scan_a(const int* __restrict__ counts, int* __restrict__ rowstart,
                         int* __restrict__ blocksums){
  __shared__ int wsum[4];
  int tid = threadIdx.x;
  int idx = blockIdx.x*1024 + tid*4;
  int v0 = (idx+0<NN)?counts[idx+0]:0;
  int v1 = (idx+1<NN)?counts[idx+1]:0;
  int v2 = (idx+2<NN)?counts[idx+2]:0;
  int v3 = (idx+3<NN)?counts[idx+3]:0;
  int s0=v0, s1=s0+v1, s2=s1+v2, s3=s2+v3;
  int lane = tid & 63, w = tid >> 6;
  int x = s3;
  #pragma unroll
  for(int off=1; off<64; off<<=1){
    int y = __shfl_up(x, off, 64);
    if(lane >= off) x += y;
  }
  if(lane==63) wsum[w] = x;
  __syncthreads();
  int woff = 0;
  for(int i=0;i<w;i++) woff += wsum[i];
  int excl = woff + (x - s3);
  if(idx+0<NN) rowstart[idx+1] = excl + s0;
  if(idx+1<NN) rowstart[idx+2] = excl + s1;
  if(idx+2<NN) rowstart[idx+3] = excl + s2;
  if(idx+3<NN) rowstart[idx+4] = excl + s3;
  if(tid==0) blocksums[blockIdx.x] = wsum[0]+wsum[1]+wsum[2]+wsum[3];
}

__global__ void k_scan_b(const int* __restrict__ blocksums, int* __restrict__ blockoff){
  int lane = threadIdx.x;
  const int nb = (NN + 1023)/1024;
  int v = (lane<nb)? blocksums[lane] : 0;
  int x = v;
  #pragma unroll
  for(int off=1; off<64; off<<=1){
    int y = __shfl_up(x, off, 64);
    if(lane >= off) x += y;
  }
  if(lane<nb) blockoff[lane] = x - v;
}

__global__ void k_scan_c(const int* __restrict__ counts, int* __restrict__ rowstart,
                         const int* __restrict__ blockoff, int* __restrict__ cursor){
  int i = blockIdx.x*blockDim.x + threadIdx.x;
  if(i < NN){
    int incl = rowstart[i+1] + blockoff[i>>10];
    rowstart[i+1] = incl;
    cursor[i] = incl - counts[i];
    if(i==0) rowstart[0] = 0;
  }
}

__global__ void k_scatter(const int* __restrict__ src, const int* __restrict__ dst,
                          int* __restrict__ cursor, int* __restrict__ ssrc){
  int e = blockIdx.x*blockDim.x + threadIdx.x;
  if(e < NE){
    int d = dst[e];
    int pos = atomicAdd(&cursor[d], 1);
    ssrc[pos] = src[e];
  }
}

// ============================ GEMM 1: h1 = x @ W1, fused a_src/a_dst dots ===
// R8 structure (best measured: 64us) minus its stall source. Single-wave
// blocks, 32 nodes x 64 cols, thread (ng=tid>>3,cg=tid&7) = 4 nodes x 8 cols.
// NO __syncthreads (wave-private LDS: compiler's fine-grained lgkmcnt waits
// replace the vmcnt(0)+lgkmcnt(0) barrier drain that exposed HBM latency
// every slice). W double-buffered in LDS (2x2KB) via register staging; x
// prefetched depth-2 in register parity buffers (unroll-2 -> static idx).

__global__ __launch_bounds__(64) void k_gemm1(
    const float* __restrict__ x, const float* __restrict__ W,
    const float* __restrict__ a_s, const float* __restrict__ a_d,
    float* __restrict__ h, float* __restrict__ as_o, float* __restrict__ ad_o){
  __shared__ float ws[2*8*64];            // 2 x (8k x 64c), 4 KB
  float4* wsv = reinterpret_cast<float4*>(ws);      // [2*128]
  const float4* Wv = reinterpret_cast<const float4*>(W);  // [256*16]
  int tid = threadIdx.x;
  int ng = tid >> 3, cg = tid & 7;
  int nb0 = blockIdx.x*32;

  const float* xrow[4];
  #pragma unroll
  for(int i=0;i<4;i++){
    int n = nb0 + ng + 8*i;
    xrow[i] = x + (size_t)((n < NN) ? n : (NN-1))*INF_DIM;
  }

  float4 acc[4][2];
  #pragma unroll
  for(int i=0;i<4;i++){ acc[i][0]=make_float4(0.f,0.f,0.f,0.f); acc[i][1]=make_float4(0.f,0.f,0.f,0.f); }

  // prologue: W slice 0 -> LDS[0]; x slices 0,1 -> register parity buffers
  {
    float4 wa = Wv[tid], wb = Wv[64+tid];
    wsv[tid] = wa; wsv[64+tid] = wb;
  }
  float4 xs[2][4][2];
  #pragma unroll
  for(int i=0;i<4;i++){
    xs[0][i][0] = *(const float4*)(xrow[i]);
    xs[0][i][1] = *(const float4*)(xrow[i] + 4);
    xs[1][i][0] = *(const float4*)(xrow[i] + 8);
    xs[1][i][1] = *(const float4*)(xrow[i] + 12);
  }

  #pragma unroll 2
  for(int st=0; st<32; ++st){
    int cur = st & 1, nxt = cur ^ 1;
    // stage W for slice st+1 into the other LDS buffer (regs -> ds_write;
    // compiler waits only the two W loads, x loads keep flying)
    if(st < 31){
      float4 wa = Wv[(st+1)*128 + tid];
      float4 wb = Wv[(st+1)*128 + 64 + tid];
      wsv[nxt*128 + tid] = wa;
      wsv[nxt*128 + 64 + tid] = wb;
    }
    // compute slice st from ws[cur] and xs[cur]
    #pragma unroll
    for(int g=0; g<2; ++g){
      float4 wf[4][2];
      #pragma unroll
      for(int kk=0;kk<4;kk++){
        wf[kk][0] = wsv[cur*128 + (g*4+kk)*16 + cg*2];
        wf[kk][1] = wsv[cur*128 + (g*4+kk)*16 + cg*2 + 1];
      }
      #pragma unroll
      for(int i=0;i<4;i++){
        float4 xv = xs[cur][i][g];
        #pragma unroll
        for(int kk=0;kk<4;kk++){
          float xk = elem4(xv, kk);
          FMA4(acc[i][0], xk, wf[kk][0])
          FMA4(acc[i][1], xk, wf[kk][1])
        }
      }
    }
    // issue x loads for slice st+2 into the buffer just consumed
    if(st < 30){
      int k0 = (st+2)*8;
      #pragma unroll
      for(int i=0;i<4;i++){
        xs[cur][i][0] = *(const float4*)(xrow[i] + k0);
        xs[cur][i][1] = *(const float4*)(xrow[i] + k0 + 4);
      }
    }
  }

  const float4* asv = reinterpret_cast<const float4*>(a_s);
  const float4* adv = reinterpret_cast<const float4*>(a_d);
  float4 asA = asv[cg*2], asB = asv[cg*2+1];
  float4 adA = adv[cg*2], adB = adv[cg*2+1];
  #pragma unroll
  for(int i=0;i<4;i++){
    int n = nb0 + ng + 8*i;
    float sv = acc[i][0].x*asA.x + acc[i][0].y*asA.y + acc[i][0].z*asA.z + acc[i][0].w*asA.w
             + acc[i][1].x*asB.x + acc[i][1].y*asB.y + acc[i][1].z*asB.z + acc[i][1].w*asB.w;
    float dv = acc[i][0].x*adA.x + acc[i][0].y*adA.y + acc[i][0].z*adA.z + acc[i][0].w*adA.w
             + acc[i][1].x*adB.x + acc[i][1].y*adB.y + acc[i][1].z*adB.z + acc[i][1].w*adB.w;
    #pragma unroll
    for(int mk=1; mk<8; mk<<=1){        // reduce across cg (lane bits 0-2)
      sv += __shfl_xor(sv, mk, 64);
      dv += __shfl_xor(dv, mk, 64);
    }
    if(n < NN){
      *(float4*)(h + (size_t)n*HIDF + cg*8)     = acc[i][0];
      *(float4*)(h + (size_t)n*HIDF + cg*8 + 4) = acc[i][1];
      if(cg==0){ as_o[n]=sv; ad_o[n]=dv; }
    }
  }
}

// ============================ Aggregation layer 1 ===========================
// Wave per node; two-phase 64-edge chunks; inner gather unrolled x8 so 8
// L2/L3 loads are in flight per step.

__global__ __launch_bounds__(256) void k_agg1(
    const float* __restrict__ h1, const float* __restrict__ as1, const float* __restrict__ ad1,
    const int* __restrict__ rowstart, const int* __restrict__ ssrc,
    float* __restrict__ r1){
  int lane = threadIdx.x & 63;
  int n = blockIdx.x*4 + (threadIdx.x >> 6);
  int rs = rowstart[n], re = rowstart[n+1];
  float adn = ad1[n];
  float m = -1e30f, l = 0.f, acc = 0.f;
  for(int base=rs; base<re; base+=64){
    int cnt = re - base; if(cnt > 64) cnt = 64;
    int s = 0; float z = -1e30f;
    if(lane < cnt){
      s = ssrc[base+lane];
      float zz = as1[s] + adn;
      z = zz > 0.f ? zz : SLOPE*zz;
    }
    float cm = z;
    #pragma unroll
    for(int off=32; off>=1; off>>=1) cm = fmaxf(cm, __shfl_xor(cm, off, 64));
    float nm = fmaxf(m, cm);
    float sc = __expf(m - nm);
    float p = (lane<cnt) ? __expf(z - nm) : 0.f;
    float cs = p;
    #pragma unroll
    for(int off=32; off>=1; off>>=1) cs += __shfl_xor(cs, off, 64);
    l = l*sc + cs;
    acc *= sc;
    int e = 0;
    for(; e+8<=cnt; e+=8){
      int se[8]; float pe[8], v[8];
      #pragma unroll
      for(int u=0;u<8;u++){ se[u] = __shfl(s, e+u, 64); pe[u] = __shfl(p, e+u, 64); }
      #pragma unroll
      for(int u=0;u<8;u++) v[u] = h1[(size_t)se[u]*HIDF + lane];
      #pragma unroll
      for(int u=0;u<8;u++) acc += pe[u]*v[u];
    }
    for(; e<cnt; ++e){
      int   se = __shfl(s, e, 64);
      float pe = __shfl(p, e, 64);
      acc += pe * h1[(size_t)se*HIDF + lane];
    }
    m = nm;
  }
  float o = (l > 0.f) ? acc/l : 0.f;
  r1[(size_t)n*HIDF + lane] = fmaxf(o, 0.f);
}

// ============================ GEMM 2: h2 = r1 @ W2, fused a dots ============
// Single-wave blocks, 32 nodes x 32 cols, thread = 4 nodes x 4 cols. W2
// (8 KB) staged once to LDS (no barrier needed: wave-private). x prefetched
// depth-2 in register parity buffers.

__global__ __launch_bounds__(64) void k_gemm2(
    const float* __restrict__ r1, const float* __restrict__ W2,
    const float* __restrict__ a_s, const float* __restrict__ a_d,
    float* __restrict__ h2, float* __restrict__ as_o, float* __restrict__ ad_o){
  __shared__ float ws2[64*32];      // [64k][32c], 8 KB
  float4* wsv = reinterpret_cast<float4*>(ws2);
  const float4* Wv = reinterpret_cast<const float4*>(W2);
  int tid = threadIdx.x;
  int ng = tid >> 3, cg = tid & 7;
  int nb0 = blockIdx.x*32;
  #pragma unroll
  for(int j=0;j<8;j++) wsv[j*64 + tid] = Wv[j*64 + tid];   // 512 float4

  const float* xrow[4];
  #pragma unroll
  for(int i=0;i<4;i++){
    int n = nb0 + ng + 8*i;
    xrow[i] = r1 + (size_t)((n < NN) ? n : (NN-1))*HIDF;
  }
  float4 acc[4];
  #pragma unroll
  for(int i=0;i<4;i++) acc[i] = make_float4(0.f,0.f,0.f,0.f);

  float4 xs[2][4][2];
  #pragma unroll
  for(int i=0;i<4;i++){
    xs[0][i][0] = *(const float4*)(xrow[i]);
    xs[0][i][1] = *(const float4*)(xrow[i] + 4);
    xs[1][i][0] = *(const float4*)(xrow[i] + 8);
    xs[1][i][1] = *(const float4*)(xrow[i] + 12);
  }

  #pragma unroll 2
  for(int st=0; st<8; ++st){
    int cur = st & 1;
    int k0 = st*8;
    #pragma unroll
    for(int g=0; g<2; ++g){
      float4 wf[4];
      #pragma unroll
      for(int kk=0;kk<4;kk++) wf[kk] = wsv[(k0 + g*4 + kk)*8 + cg];
      #pragma unroll
      for(int i=0;i<4;i++){
        float4 xv = xs[cur][i][g];
        #pragma unroll
        for(int kk=0;kk<4;kk++){
          float xk = elem4(xv, kk);
          FMA4(acc[i], xk, wf[kk])
        }
      }
    }
    if(st < 6){
      int kn = (st+2)*8;
      #pragma unroll
      for(int i=0;i<4;i++){
        xs[cur][i][0] = *(const float4*)(xrow[i] + kn);
        xs[cur][i][1] = *(const float4*)(xrow[i] + kn + 4);
      }
    }
  }

  const float4* asv = reinterpret_cast<const float4*>(a_s);
  const float4* adv = reinterpret_cast<const float4*>(a_d);
  float4 as4 = asv[cg], ad4 = adv[cg];
  #pragma unroll
  for(int i=0;i<4;i++){
    int n = nb0 + ng + 8*i;
    float sv = acc[i].x*as4.x + acc[i].y*as4.y + acc[i].z*as4.z + acc[i].w*as4.w;
    float dv = acc[i].x*ad4.x + acc[i].y*ad4.y + acc[i].z*ad4.z + acc[i].w*ad4.w;
    #pragma unroll
    for(int mk=1; mk<8; mk<<=1){
      sv += __shfl_xor(sv, mk, 64);
      dv += __shfl_xor(dv, mk, 64);
    }
    if(n < NN){
      *(float4*)(h2 + (size_t)n*NC + cg*4) = acc[i];
      if(cg==0){ as_o[n]=sv; ad_o[n]=dv; }
    }
  }
}

// ============================ Aggregation layer 2 ===========================
// Half-wave (32 lanes) per node; inner gather unrolled x8.

__global__ __launch_bounds__(256) void k_agg2(
    const float* __restrict__ h2, const float* __restrict__ as2, const float* __restrict__ ad2,
    const int* __restrict__ rowstart, const int* __restrict__ ssrc,
    float* __restrict__ out){
  int tid = threadIdx.x;
  int c = tid & 31;
  int n = blockIdx.x*8 + (tid >> 5);
  int rs = rowstart[n], re = rowstart[n+1];
  float adn = ad2[n];
  float m = -1e30f, l = 0.f, acc = 0.f;
  for(int base=rs; base<re; base+=32){
    int cnt = re - base; if(cnt > 32) cnt = 32;
    int s = 0; float z = -1e30f;
    if(c < cnt){
      s = ssrc[base+c];
      float zz = as2[s] + adn;
      z = zz > 0.f ? zz : SLOPE*zz;
    }
    float cm = z;
    #pragma unroll
    for(int off=16; off>=1; off>>=1) cm = fmaxf(cm, __shfl_xor(cm, off, 32));
    float nm = fmaxf(m, cm);
    float sc = __expf(m - nm);
    float p = (c<cnt) ? __expf(z - nm) : 0.f;
    float cs = p;
    #pragma unroll
    for(int off=16; off>=1; off>>=1) cs += __shfl_xor(cs, off, 32);
    l = l*sc + cs;
    acc *= sc;
    int e = 0;
    for(; e+8<=cnt; e+=8){
      int se[8]; float pe[8], v[8];
      #pragma unroll
      for(int u=0;u<8;u++){ se[u] = __shfl(s, e+u, 32); pe[u] = __shfl(p, e+u, 32); }
      #pragma unroll
      for(int u=0;u<8;u++) v[u] = h2[(size_t)se[u]*NC + c];
      #pragma unroll
      for(int u=0;u<8;u++) acc += pe[u]*v[u];
    }
    for(; e<cnt; ++e){
      int   se = __shfl(s, e, 32);
      float pe = __shfl(p, e, 32);
      acc += pe * h2[(size_t)se*NC + c];
    }
    m = nm;
  }
  out[(size_t)n*NC + c] = (l > 0.f) ? acc/l : 0.f;
}

// ============================ launch ============================

extern "C" void kernel_launch(void* const* d_in, const int* in_sizes, int n_in,
                              void* d_out, int out_size, void* d_ws, size_t ws_size,
                              hipStream_t stream){
  const float* x   = (const float*)d_in[0];
  const int*   ei  = (const int*)d_in[1];
  const float* W1  = (const float*)d_in[2];
  const float* a1s = (const float*)d_in[3];
  const float* a1d = (const float*)d_in[4];
  const float* W2  = (const float*)d_in[5];
  const float* a2s = (const float*)d_in[6];
  const float* a2d = (const float*)d_in[7];
  const int* srcIdx = ei;
  const int* dstIdx = ei + NE;
  float* out = (float*)d_out;

  char* wsp = (char*)d_ws;
  size_t off = 0;
  auto alloc = [&](size_t bytes)->void*{
    void* p = wsp + off;
    off = (off + bytes + 255) & ~(size_t)255;
    return p;
  };
  int* counts    = (int*)alloc((size_t)NN*sizeof(int));
  int* rowstart  = (int*)alloc((size_t)(NN+1)*sizeof(int));
  int* cursor    = (int*)alloc((size_t)NN*sizeof(int));
  int* blocksums = (int*)alloc(64*sizeof(int));
  int* blockoff  = (int*)alloc(64*sizeof(int));
  int* ssrc      = (int*)alloc((size_t)NE*sizeof(int));
  float* h1      = (float*)alloc((size_t)NN*HIDF*sizeof(float));
  float* as1     = (float*)alloc((size_t)NN*sizeof(float));
  float* ad1     = (float*)alloc((size_t)NN*sizeof(float));
  float* r1      = (float*)alloc((size_t)NN*HIDF*sizeof(float));
  float* h2  = h1;
  float* as2 = as1;
  float* ad2 = ad1;

  k_zero   <<<(NN+255)/256, 256, 0, stream>>>(counts);
  k_hist   <<<(NE+255)/256, 256, 0, stream>>>(dstIdx, counts);
  k_scan_a <<<(NN+1023)/1024, 256, 0, stream>>>(counts, rowstart, blocksums);
  k_scan_b <<<1, 64, 0, stream>>>(blocksums, blockoff);
  k_scan_c <<<(NN+255)/256, 256, 0, stream>>>(counts, rowstart, blockoff, cursor);
  k_scatter<<<(NE+255)/256, 256, 0, stream>>>(srcIdx, dstIdx, cursor, ssrc);

  k_gemm1<<<(NN+31)/32, 64, 0, stream>>>(x, W1, a1s, a1d, h1, as1, ad1);
  k_agg1 <<<NN/4, 256, 0, stream>>>(h1, as1, ad1, rowstart, ssrc, r1);

  k_gemm2<<<(NN+31)/32, 64, 0, stream>>>(r1, W2, a2s, a2d, h2, as2, ad2);
  k_agg2 <<<NN/8, 256, 0, stream>>>(h2, as2, ad2, rowstart, ssrc, out);
}